// Round 6
// baseline (39446.994 us; speedup 1.0000x reference)
//
#include <hip/hip_runtime.h>
#include <hip/hip_bf16.h>
#include <math.h>

typedef __attribute__((ext_vector_type(8))) short bf16x8;
typedef __attribute__((ext_vector_type(4))) float f32x4;

#define VOCAB 50257
#define VPAD  50304
#define NCT   (VPAD / 16)      // 3144 col-tiles
#define DIM   1024
#define HID   1024
#define TH3   3072
#define NL    2
#define NB    64
#define RCH   16
#define GKC   8                // GRU K-chunk-groups per matrix (K=128 each)
#define NBLK  768
#define NTHR  256

// ---------- fp32 -> bf16(hi) + bf16(lo) Dekker split, RNE both ----------
__device__ __forceinline__ unsigned short bf16_rne(float f) {
    unsigned int u = __float_as_uint(f);
    unsigned int r = u + 0x7FFFu + ((u >> 16) & 1u);
    return (unsigned short)(r >> 16);
}
__device__ __forceinline__ void split1(float f, unsigned short& h, unsigned short& l) {
    unsigned short hb = bf16_rne(f);
    float fh = __uint_as_float(((unsigned int)hb) << 16);
    h = hb;
    l = bf16_rne(f - fh);
}

// tile layout: [rowtile16][kchunk32][lane64][j8]; lane = (k>>3 & 3)*16 + (row&15)
__device__ __forceinline__ size_t tpos(int r, int k) {
    int ct = r >> 4, colr = r & 15, kc = k >> 5, kg = (k >> 3) & 3, j = k & 7;
    return ((((size_t)ct * 32 + kc) * 64) + (kg * 16 + colr)) * 8 + j;
}

// ---------- device-scope grid barrier (all NBLK blocks co-resident) ----------
__device__ __forceinline__ void gbar(unsigned* cnt, unsigned* gen) {
    __syncthreads();                       // all block work done, vmcnt drained
    if (threadIdx.x == 0) {
        __builtin_amdgcn_fence(__ATOMIC_RELEASE, "agent");
        unsigned g = __hip_atomic_load(gen, __ATOMIC_RELAXED, __HIP_MEMORY_SCOPE_AGENT);
        unsigned a = __hip_atomic_fetch_add(cnt, 1u, __ATOMIC_ACQ_REL, __HIP_MEMORY_SCOPE_AGENT);
        if (a == gridDim.x - 1) {
            __hip_atomic_store(cnt, 0u, __ATOMIC_RELAXED, __HIP_MEMORY_SCOPE_AGENT);
            __hip_atomic_store(gen, g + 1u, __ATOMIC_RELEASE, __HIP_MEMORY_SCOPE_AGENT);
        } else {
            while (__hip_atomic_load(gen, __ATOMIC_ACQUIRE, __HIP_MEMORY_SCOPE_AGENT) == g)
                __builtin_amdgcn_s_sleep(8);
        }
        __builtin_amdgcn_fence(__ATOMIC_ACQUIRE, "agent");
    }
    __syncthreads();
}

struct KP {
    const float *emb, *w_ih, *w_hh, *b_ih, *b_hh, *w_proj, *b_proj, *h0;
    const int   *start;
    unsigned short *bpjh, *bpjl;
    unsigned short *gwh[4], *gwl[4];       // [l*2+m] m0=ih m1=hh
    unsigned short *hth, *htl;             // layer stride 65536 elems
    float *hbuf, *gpart, *logits, *red;
    int   *tok;
    unsigned *cnt, *gen;
    float *out_logp, *out_tok;
    int Vt, Tt;
};

__global__ void __launch_bounds__(NTHR, 4) k_persist(KP p) {
    const int bid = blockIdx.x, tid = threadIdx.x;
    const int wav = tid >> 6, lane = tid & 63;
    const int colr = lane & 15, kg = lane >> 4;
    __shared__ float sm[NTHR]; __shared__ int si[NTHR]; __shared__ float ss[NTHR];

    // ================= precompute (once per launch) =================
    for (int idx = bid * NTHR + tid; idx < NL * NB * HID; idx += NBLK * NTHR) {
        float v = p.h0[idx];
        p.hbuf[idx] = v;
        int l = idx >> 16, b = (idx >> 10) & 63, i = idx & 1023;
        unsigned short h, lo;
        split1(v, h, lo);
        size_t q = (size_t)l * 65536 + tpos(b, i);
        p.hth[q] = h; p.htl[q] = lo;
    }
    if (bid == 0 && tid < NB) p.tok[tid] = p.start[0];
    for (size_t idx = (size_t)bid * NTHR + tid; idx < (size_t)VPAD * 1024; idx += (size_t)NBLK * NTHR) {
        int r = (int)(idx >> 10), k = (int)(idx & 1023);
        float v = (r < p.Vt) ? p.w_proj[(size_t)r * 1024 + k] : 0.f;
        unsigned short h, l; split1(v, h, l);
        size_t q = tpos(r, k);
        p.bpjh[q] = h; p.bpjl[q] = l;
    }
    for (int w = 0; w < 4; ++w) {                 // w = l*2+m
        const float* W = (w & 1) ? p.w_hh + (size_t)(w >> 1) * TH3 * HID
                                 : p.w_ih + (size_t)(w >> 1) * TH3 * DIM;
        unsigned short* th = p.gwh[w];
        unsigned short* tl = p.gwl[w];
        for (size_t idx = (size_t)bid * NTHR + tid; idx < (size_t)TH3 * 1024; idx += (size_t)NBLK * NTHR) {
            int r = (int)(idx >> 10), k = (int)(idx & 1023);
            float v = W[(size_t)r * 1024 + k];
            unsigned short h, l; split1(v, h, l);
            size_t q = tpos(r, k);
            th[q] = h; tl[q] = l;
        }
    }
    gbar(p.cnt, p.gen);

    // ================= T-step loop =================
    for (int t = 0; t < p.Tt; ++t) {
        // ---- GRU layers ----
        for (int l = 0; l < NL; ++l) {
            {
                int u = bid * 4 + wav;                     // 0..3071
                int m = u / 1536, rem = u % 1536;
                int kcg = rem / 192, ct = rem % 192;
                int kc0 = kcg * 4;                         // K=128 per wave: kc in [kcg*4, kcg*4+3]
                const bf16x8* B8h = (const bf16x8*)p.gwh[l * 2 + m];
                const bf16x8* B8l = (const bf16x8*)p.gwl[l * 2 + m];
                const unsigned short* Ath = (m == 0) ? p.hth : p.hth + (size_t)l * 65536;
                const unsigned short* Atl = (m == 0) ? p.htl : p.htl + (size_t)l * 65536;
                const bf16x8* A8h = (const bf16x8*)Ath;
                const bf16x8* A8l = (const bf16x8*)Atl;
                const bool gather = (l == 0 && m == 0);    // x = emb[tok]
                f32x4 acc[4];
#pragma unroll
                for (int mt = 0; mt < 4; ++mt) acc[mt] = (f32x4){0.f, 0.f, 0.f, 0.f};
#pragma unroll
                for (int i = 0; i < 4; ++i) {
                    int kc = kc0 + i;
                    bf16x8 bh = B8h[((size_t)ct * 32 + kc) * 64 + lane];
                    bf16x8 bl = B8l[((size_t)ct * 32 + kc) * 64 + lane];
#pragma unroll
                    for (int mt = 0; mt < 4; ++mt) {
                        bf16x8 ah, al;
                        if (gather) {
                            int brow = mt * 16 + colr;
                            int k = kc * 32 + kg * 8;
                            const float* er = p.emb + (size_t)p.tok[brow] * DIM + k;
                            float4 e0 = *(const float4*)er;
                            float4 e1 = *(const float4*)(er + 4);
                            float ev[8] = {e0.x, e0.y, e0.z, e0.w, e1.x, e1.y, e1.z, e1.w};
#pragma unroll
                            for (int j = 0; j < 8; ++j) {
                                unsigned short h, lo;
                                split1(ev[j], h, lo);
                                ah[j] = (short)h; al[j] = (short)lo;
                            }
                        } else {
                            ah = A8h[(mt * 32 + kc) * 64 + lane];
                            al = A8l[(mt * 32 + kc) * 64 + lane];
                        }
                        acc[mt] = __builtin_amdgcn_mfma_f32_16x16x32_bf16(ah, bh, acc[mt], 0, 0, 0);
                        acc[mt] = __builtin_amdgcn_mfma_f32_16x16x32_bf16(al, bh, acc[mt], 0, 0, 0);
                        acc[mt] = __builtin_amdgcn_mfma_f32_16x16x32_bf16(ah, bl, acc[mt], 0, 0, 0);
                    }
                }
                float* out = p.gpart + (size_t)(m * GKC + kcg) * 64 * TH3;
#pragma unroll
                for (int mt = 0; mt < 4; ++mt)
#pragma unroll
                    for (int r = 0; r < 4; ++r)
                        out[(size_t)(mt * 16 + kg * 4 + r) * TH3 + ct * 16 + colr] = acc[mt][r];
            }
            gbar(p.cnt, p.gen);
            // ---- gate ----
            {
                int idx = bid * NTHR + tid;
                if (idx < NB * HID) {
                    int b = idx >> 10, i = idx & 1023;
                    const float* bih = p.b_ih + (size_t)l * TH3;
                    const float* bhh = p.b_hh + (size_t)l * TH3;
                    float ir = bih[i], iz = bih[HID + i], in = bih[2 * HID + i];
                    float hr = bhh[i], hz = bhh[HID + i], hn = bhh[2 * HID + i];
#pragma unroll
                    for (int kc = 0; kc < GKC; ++kc) {
                        const float* gi = p.gpart + ((size_t)kc * 64 + b) * TH3;
                        const float* gh = p.gpart + ((size_t)(GKC + kc) * 64 + b) * TH3;
                        ir += gi[i]; iz += gi[HID + i]; in += gi[2 * HID + i];
                        hr += gh[i]; hz += gh[HID + i]; hn += gh[2 * HID + i];
                    }
                    float r = 1.f / (1.f + expf(-(ir + hr)));
                    float z = 1.f / (1.f + expf(-(iz + hz)));
                    float n = tanhf(in + r * hn);
                    float* hb = p.hbuf + (size_t)l * NB * HID;
                    float hold = hb[idx];
                    float hnew = (1.f - z) * n + z * hold;
                    hb[idx] = hnew;
                    unsigned short h, lo;
                    split1(hnew, h, lo);
                    size_t q = (size_t)l * 65536 + tpos(b, i);
                    p.hth[q] = h; p.htl[q] = lo;
                }
            }
            gbar(p.cnt, p.gen);
        }
        // ---- projection: col-tile units round-robin; wave handles mt=wav ----
        {
            const bf16x8* A8h = (const bf16x8*)(p.hth + 65536);
            const bf16x8* A8l = (const bf16x8*)(p.htl + 65536);
            const int mt = wav;
            for (int ct = bid; ct < NCT; ct += NBLK) {
                const bf16x8* B8h = (const bf16x8*)p.bpjh + (size_t)ct * 32 * 64 + lane;
                const bf16x8* B8l = (const bf16x8*)p.bpjl + (size_t)ct * 32 * 64 + lane;
                f32x4 acc = (f32x4){0.f, 0.f, 0.f, 0.f};
#pragma unroll 2
                for (int kc = 0; kc < 32; ++kc) {
                    bf16x8 bh = B8h[kc * 64];
                    bf16x8 bl = B8l[kc * 64];
                    bf16x8 ah = A8h[(mt * 32 + kc) * 64 + lane];
                    bf16x8 al = A8l[(mt * 32 + kc) * 64 + lane];
                    acc = __builtin_amdgcn_mfma_f32_16x16x32_bf16(ah, bh, acc, 0, 0, 0);
                    acc = __builtin_amdgcn_mfma_f32_16x16x32_bf16(al, bh, acc, 0, 0, 0);
                    acc = __builtin_amdgcn_mfma_f32_16x16x32_bf16(ah, bl, acc, 0, 0, 0);
                }
                int col = ct * 16 + colr;
                float bv = (col < p.Vt) ? p.b_proj[col] : 0.f;
#pragma unroll
                for (int r = 0; r < 4; ++r)
                    p.logits[(size_t)(mt * 16 + kg * 4 + r) * VPAD + col] = acc[r] + bv;
            }
        }
        gbar(p.cnt, p.gen);
        // ---- reduce: per-(b,chunk) max/argmax/sumexp ----
        {
            const int cs = (p.Vt + RCH - 1) / RCH;
            for (int u = bid; u < NB * RCH; u += NBLK) {
                int b = u >> 4, ch = u & 15;
                int v0 = ch * cs, v1 = min(v0 + cs, p.Vt);
                const float* row = p.logits + (size_t)b * VPAD;
                float m = -INFINITY; int mi = 0;
                for (int v = v0 + tid; v < v1; v += NTHR) {
                    float x = row[v];
                    if (x > m) { m = x; mi = v; }
                }
                sm[tid] = m; si[tid] = mi;
                __syncthreads();
                for (int s = 128; s > 0; s >>= 1) {
                    if (tid < s) {
                        float vo = sm[tid + s]; int io = si[tid + s];
                        if (vo > sm[tid] || (vo == sm[tid] && io < si[tid])) { sm[tid] = vo; si[tid] = io; }
                    }
                    __syncthreads();
                }
                float mb = sm[0];
                float a = 0.f;
                for (int v = v0 + tid; v < v1; v += NTHR) a += expf(row[v] - mb);
                ss[tid] = a;
                __syncthreads();
                for (int s = 128; s > 0; s >>= 1) {
                    if (tid < s) ss[tid] += ss[tid + s];
                    __syncthreads();
                }
                if (tid == 0)
                    ((float4*)p.red)[b * RCH + ch] = make_float4(mb, ss[0], (float)si[0], 0.f);
                __syncthreads();
            }
        }
        gbar(p.cnt, p.gen);
        // ---- final: logp write + token select ----
        {
            for (int u = bid; u < NB * 25; u += NBLK) {
                int b = u / 25, ch = u % 25;
                float mg = -INFINITY, ig = 0.f;
#pragma unroll
                for (int c = 0; c < RCH; ++c) {
                    float4 q = ((const float4*)p.red)[b * RCH + c];
                    if (q.x > mg) { mg = q.x; ig = q.z; }
                    else if (q.x == mg && q.z < ig) { ig = q.z; }
                }
                float sg = 0.f;
#pragma unroll
                for (int c = 0; c < RCH; ++c) {
                    float4 q = ((const float4*)p.red)[b * RCH + c];
                    sg += q.y * expf(q.x - mg);
                }
                float lse = mg + logf(sg);
                const float* row = p.logits + (size_t)b * VPAD;
                float* orow = p.out_logp + ((size_t)b * p.Tt + t) * p.Vt;
                int base = ch * 2048;
#pragma unroll
                for (int j = 0; j < 8; ++j) {
                    int v = base + tid + j * NTHR;
                    if (v < p.Vt) orow[v] = row[v] - lse;
                }
                if (ch == 0 && tid == 0) {
                    p.tok[b] = (int)ig;
                    p.out_tok[(size_t)b * p.Tt + t] = ig;
                }
            }
        }
        gbar(p.cnt, p.gen);
    }
}

// ================= fallback (round-1) path =================

__global__ __launch_bounds__(256) void k_init(const float* __restrict__ h0,
                                              const int* __restrict__ start_tok,
                                              float* hbuf, unsigned short* hhi,
                                              unsigned short* hlo, int* tok) {
    int idx = blockIdx.x * 256 + threadIdx.x;
    if (idx < NL * NB * HID) {
        float v = h0[idx];
        hbuf[idx] = v;
        split1(v, hhi[idx], hlo[idx]);
    }
    if (idx < NB) tok[idx] = start_tok[0];
}

__global__ __launch_bounds__(256) void k_prep_x(const float* __restrict__ emb,
                                                const int* __restrict__ tok,
                                                unsigned short* xhi, unsigned short* xlo) {
    int idx = blockIdx.x * 256 + threadIdx.x;
    int b = idx >> 10, k = idx & 1023;
    float v = emb[(size_t)tok[b] * DIM + k];
    split1(v, xhi[idx], xlo[idx]);
}

__device__ __forceinline__ void mm_wave(const unsigned short* __restrict__ Ahi,
                                        const unsigned short* __restrict__ Alo,
                                        const float* __restrict__ W,
                                        int Ntot, int col, int k0, int klen,
                                        f32x4* acc) {
    const int lane = threadIdx.x & 63;
    const int colr = lane & 15;
    const int kg   = lane >> 4;
    const int colc = col < Ntot ? col : Ntot - 1;
    const float* wrow = W + (size_t)colc * 1024;
    for (int k = k0; k < k0 + klen; k += 32) {
        int ka = k + kg * 8;
        float4 b0 = *(const float4*)(wrow + ka);
        float4 b1 = *(const float4*)(wrow + ka + 4);
        float bv[8] = {b0.x, b0.y, b0.z, b0.w, b1.x, b1.y, b1.z, b1.w};
        bf16x8 bhi, blo;
#pragma unroll
        for (int j = 0; j < 8; ++j) {
            unsigned short h, l;
            split1(bv[j], h, l);
            bhi[j] = (short)h;
            blo[j] = (short)l;
        }
#pragma unroll
        for (int mt = 0; mt < 4; ++mt) {
            const bf16x8 ahi = *(const bf16x8*)(Ahi + (((mt * 16 + colr) << 10) + ka));
            const bf16x8 alo = *(const bf16x8*)(Alo + (((mt * 16 + colr) << 10) + ka));
            acc[mt] = __builtin_amdgcn_mfma_f32_16x16x32_bf16(ahi, bhi, acc[mt], 0, 0, 0);
            acc[mt] = __builtin_amdgcn_mfma_f32_16x16x32_bf16(alo, bhi, acc[mt], 0, 0, 0);
            acc[mt] = __builtin_amdgcn_mfma_f32_16x16x32_bf16(ahi, blo, acc[mt], 0, 0, 0);
        }
    }
}

__global__ __launch_bounds__(256) void k_mm_gru(const unsigned short* __restrict__ Axhi,
                                                const unsigned short* __restrict__ Axlo,
                                                const unsigned short* __restrict__ Ahhi,
                                                const unsigned short* __restrict__ Ahlo,
                                                const float* __restrict__ Wih,
                                                const float* __restrict__ Whh,
                                                float* __restrict__ gpart) {
    const int mat = blockIdx.z;
    const int kc  = blockIdx.y;
    const int wav = threadIdx.x >> 6;
    const int lane = threadIdx.x & 63;
    const int col = blockIdx.x * 64 + wav * 16 + (lane & 15);
    const unsigned short* Ahi = mat ? Ahhi : Axhi;
    const unsigned short* Alo = mat ? Ahlo : Axlo;
    const float* W = mat ? Whh : Wih;
    f32x4 acc[4] = {{0.f,0.f,0.f,0.f},{0.f,0.f,0.f,0.f},{0.f,0.f,0.f,0.f},{0.f,0.f,0.f,0.f}};
    mm_wave(Ahi, Alo, W, TH3, col, kc * 512, 512, acc);
    float* out = gpart + (size_t)(mat * 2 + kc) * NB * TH3;
    const int kg = lane >> 4;
#pragma unroll
    for (int mt = 0; mt < 4; ++mt)
#pragma unroll
        for (int r = 0; r < 4; ++r)
            out[(size_t)(mt * 16 + kg * 4 + r) * TH3 + col] = acc[mt][r];
}

__global__ __launch_bounds__(256) void k_gate(const float* __restrict__ gpart,
                                              const float* __restrict__ bih,
                                              const float* __restrict__ bhh,
                                              float* hbuf, unsigned short* hhi,
                                              unsigned short* hlo) {
    int idx = blockIdx.x * 256 + threadIdx.x;
    int b = idx >> 10, i = idx & 1023;
    const float* g00 = gpart;
    const float* g01 = gpart + (size_t)1 * NB * TH3;
    const float* g10 = gpart + (size_t)2 * NB * TH3;
    const float* g11 = gpart + (size_t)3 * NB * TH3;
    size_t o = (size_t)b * TH3;
    float ir = g00[o + i]            + g01[o + i]            + bih[i];
    float iz = g00[o + HID + i]      + g01[o + HID + i]      + bih[HID + i];
    float in = g00[o + 2 * HID + i]  + g01[o + 2 * HID + i]  + bih[2 * HID + i];
    float hr = g10[o + i]            + g11[o + i]            + bhh[i];
    float hz = g10[o + HID + i]      + g11[o + HID + i]      + bhh[HID + i];
    float hn = g10[o + 2 * HID + i]  + g11[o + 2 * HID + i]  + bhh[2 * HID + i];
    float r = 1.f / (1.f + expf(-(ir + hr)));
    float z = 1.f / (1.f + expf(-(iz + hz)));
    float n = tanhf(in + r * hn);
    float hold = hbuf[idx];
    float hnew = (1.f - z) * n + z * hold;
    hbuf[idx] = hnew;
    split1(hnew, hhi[idx], hlo[idx]);
}

__global__ __launch_bounds__(256) void k_mm_proj(const unsigned short* __restrict__ Ahi,
                                                 const unsigned short* __restrict__ Alo,
                                                 const float* __restrict__ Wp,
                                                 const float* __restrict__ bp,
                                                 float* __restrict__ logits, int Vt) {
    const int wav = threadIdx.x >> 6;
    const int lane = threadIdx.x & 63;
    const int col = blockIdx.x * 64 + wav * 16 + (lane & 15);
    f32x4 acc[4] = {{0.f,0.f,0.f,0.f},{0.f,0.f,0.f,0.f},{0.f,0.f,0.f,0.f},{0.f,0.f,0.f,0.f}};
    mm_wave(Ahi, Alo, Wp, Vt, col, 0, 1024, acc);
    if (col < Vt) {
        float bv = bp[col];
        const int kg = lane >> 4;
#pragma unroll
        for (int mt = 0; mt < 4; ++mt)
#pragma unroll
            for (int r = 0; r < 4; ++r)
                logits[(size_t)(mt * 16 + kg * 4 + r) * Vt + col] = acc[mt][r] + bv;
    }
}

__global__ __launch_bounds__(256) void k_reduce(const float* __restrict__ logits,
                                                float* __restrict__ red, int Vt, int ldl) {
    const int b = blockIdx.y, ch = blockIdx.x, tid = threadIdx.x;
    const int cs = (Vt + RCH - 1) / RCH;
    const int v0 = ch * cs;
    const int v1 = min(v0 + cs, Vt);
    const float* row = logits + (size_t)b * ldl;
    float m = -INFINITY; int mi = 0;
    for (int v = v0 + tid; v < v1; v += 256) {
        float x = row[v];
        if (x > m) { m = x; mi = v; }
    }
    __shared__ float sm[256]; __shared__ int si[256]; __shared__ float ss[256];
    sm[tid] = m; si[tid] = mi;
    __syncthreads();
    for (int s = 128; s > 0; s >>= 1) {
        if (tid < s) {
            float vo = sm[tid + s]; int io = si[tid + s];
            if (vo > sm[tid] || (vo == sm[tid] && io < si[tid])) { sm[tid] = vo; si[tid] = io; }
        }
        __syncthreads();
    }
    float mb = sm[0];
    float acc = 0.f;
    for (int v = v0 + tid; v < v1; v += 256) acc += expf(row[v] - mb);
    ss[tid] = acc;
    __syncthreads();
    for (int s = 128; s > 0; s >>= 1) {
        if (tid < s) ss[tid] += ss[tid + s];
        __syncthreads();
    }
    if (tid == 0)
        ((float4*)red)[b * RCH + ch] = make_float4(mb, ss[0], (float)si[0], 0.f);
}

__global__ __launch_bounds__(256) void k_final(const float* __restrict__ logits,
                                               const float* __restrict__ red,
                                               float* __restrict__ out_logp,
                                               float* __restrict__ out_tok,
                                               int* __restrict__ toknext,
                                               int Vt, int ldl, int Tt, int t) {
    const int b = blockIdx.y, tid = threadIdx.x;
    float mg = -INFINITY, ig = 0.f;
#pragma unroll
    for (int c = 0; c < RCH; ++c) {
        float4 p = ((const float4*)red)[b * RCH + c];
        if (p.x > mg) { mg = p.x; ig = p.z; }
        else if (p.x == mg && p.z < ig) { ig = p.z; }
    }
    float sg = 0.f;
#pragma unroll
    for (int c = 0; c < RCH; ++c) {
        float4 p = ((const float4*)red)[b * RCH + c];
        sg += p.y * expf(p.x - mg);
    }
    float lse = mg + logf(sg);
    const float* row = logits + (size_t)b * ldl;
    float* orow = out_logp + ((size_t)b * Tt + t) * Vt;
    const int base = blockIdx.x * 2048;
#pragma unroll
    for (int j = 0; j < 8; ++j) {
        int v = base + tid + j * 256;
        if (v < Vt) orow[v] = row[v] - lse;
    }
    if (blockIdx.x == 0 && tid == 0) {
        toknext[b] = (int)ig;
        out_tok[(size_t)b * Tt + t] = ig;
    }
}

extern "C" void kernel_launch(void* const* d_in, const int* in_sizes, int n_in,
                              void* d_out, int out_size, void* d_ws, size_t ws_size,
                              hipStream_t stream) {
    const float* emb    = (const float*)d_in[0];
    const float* w_ih   = (const float*)d_in[1];
    const float* w_hh   = (const float*)d_in[2];
    const float* b_ih   = (const float*)d_in[3];
    const float* b_hh   = (const float*)d_in[4];
    const float* w_proj = (const float*)d_in[5];
    const float* b_proj = (const float*)d_in[6];
    const float* h0     = (const float*)d_in[7];
    const int*   start  = (const int*)d_in[9];

    const int Vt = in_sizes[5] / HID;                 // 50257
    const int Tt = (int)((size_t)out_size / ((size_t)NB * (Vt + 1)));  // 32

    float* out_logp = (float*)d_out;
    float* out_tok  = (float*)d_out + (size_t)NB * Tt * Vt;

    const size_t SZ_BPROJ = (size_t)NCT * 32 * 64 * 8 * 2;
    const size_t SZ_GRUW  = (size_t)(TH3 / 16) * 32 * 64 * 8 * 2;
    const size_t SZ_HT    = (size_t)65536 * 2;

    char* ws = (char*)d_ws;
    size_t used = 0;
    auto alloc = [&](size_t bytes) {
        char* p = ws + used;
        used += (bytes + 255) & ~(size_t)255;
        return p;
    };
    KP p;
    p.emb = emb; p.w_ih = w_ih; p.w_hh = w_hh; p.b_ih = b_ih; p.b_hh = b_hh;
    p.w_proj = w_proj; p.b_proj = b_proj; p.h0 = h0; p.start = start;
    p.out_logp = out_logp; p.out_tok = out_tok; p.Vt = Vt; p.Tt = Tt;

    p.logits = (float*)alloc((size_t)NB * VPAD * 4);
    p.bpjh = (unsigned short*)alloc(SZ_BPROJ);
    p.bpjl = (unsigned short*)alloc(SZ_BPROJ);
    for (int i = 0; i < 4; ++i) {
        p.gwh[i] = (unsigned short*)alloc(SZ_GRUW);
        p.gwl[i] = (unsigned short*)alloc(SZ_GRUW);
    }
    p.hth = (unsigned short*)alloc(NL * SZ_HT);
    p.htl = (unsigned short*)alloc(NL * SZ_HT);
    p.hbuf = (float*)alloc((size_t)NL * NB * HID * 4);
    p.gpart = (float*)alloc((size_t)2 * GKC * 64 * TH3 * 4);
    p.red = (float*)alloc((size_t)NB * RCH * 16);
    p.tok = (int*)alloc(256);
    unsigned* bar = (unsigned*)alloc(256);
    p.cnt = bar;
    p.gen = bar + 32;

    if (ws_size >= used) {
        // ---- persistent single-kernel path ----
        hipMemsetAsync(bar, 0, 256, stream);
        k_persist<<<NBLK, NTHR, 0, stream>>>(p);
    } else {
        // ---- fallback (round-1) path ----
        char* w = (char*)d_ws;
        float* logitsF       = (float*)w;  w += (size_t)NB * Vt * 4;
        unsigned short* a0hi = (unsigned short*)w;  w += (size_t)NB * DIM * 2;
        unsigned short* a0lo = (unsigned short*)w;  w += (size_t)NB * DIM * 2;
        float* hbufF         = (float*)w;  w += (size_t)NL * NB * HID * 4;
        unsigned short* hhi  = (unsigned short*)w;  w += (size_t)NL * NB * HID * 2;
        unsigned short* hlo  = (unsigned short*)w;  w += (size_t)NL * NB * HID * 2;
        float* gpartF        = (float*)w;  w += (size_t)4 * NB * TH3 * 4;
        float* redF          = (float*)w;  w += (size_t)NB * RCH * 16;
        int* tokF            = (int*)w;    w += 256;

        k_init<<<(NL * NB * HID + 255) / 256, 256, 0, stream>>>(h0, start, hbufF, hhi, hlo, tokF);
        for (int t = 0; t < Tt; ++t) {
            k_prep_x<<<NB * DIM / 256, 256, 0, stream>>>(emb, tokF, a0hi, a0lo);
            for (int l = 0; l < NL; ++l) {
                const unsigned short* Axhi = (l == 0) ? a0hi : hhi;
                const unsigned short* Axlo = (l == 0) ? a0lo : hlo;
                const unsigned short* Ahhi = hhi + (size_t)l * NB * HID;
                const unsigned short* Ahlo = hlo + (size_t)l * NB * HID;
                k_mm_gru<<<dim3(TH3 / 64, 2, 2), 256, 0, stream>>>(
                    Axhi, Axlo, Ahhi, Ahlo,
                    w_ih + (size_t)l * TH3 * DIM, w_hh + (size_t)l * TH3 * HID, gpartF);
                k_gate<<<NB * HID / 256, 256, 0, stream>>>(
                    gpartF, b_ih + (size_t)l * TH3, b_hh + (size_t)l * TH3,
                    hbufF + (size_t)l * NB * HID, hhi + (size_t)l * NB * HID,
                    hlo + (size_t)l * NB * HID);
            }
            k_mm_proj<<<dim3((Vt + 63) / 64, 1, 1), 256, 0, stream>>>(
                hhi + (size_t)NB * HID, hlo + (size_t)NB * HID, w_proj, b_proj, logitsF, Vt);
            k_reduce<<<dim3(RCH, NB), 256, 0, stream>>>(logitsF, redF, Vt, Vt);
            k_final<<<dim3((Vt + 2047) / 2048, NB), 256, 0, stream>>>(
                logitsF, redF, out_logp, out_tok, tokF, Vt, Vt, Tt, t);
        }
    }
}

// Round 7
// 12454.680 us; speedup vs baseline: 3.1672x; 3.1672x over previous
//
#include <hip/hip_runtime.h>
#include <hip/hip_bf16.h>
#include <math.h>

typedef __attribute__((ext_vector_type(8))) short bf16x8;
typedef __attribute__((ext_vector_type(4))) float f32x4;

#define VOCAB 50257
#define VPAD  50304
#define NCT   (VPAD / 16)      // 3144 col-tiles
#define DIM   1024
#define HID   1024
#define TH3   3072
#define NL    2
#define NB    64
#define RCH   16
#define GKC   8                // GRU K-chunk-groups per matrix (K=128 each)
#define NBLK  768
#define NTHR  256
#define NGRP  24               // 768 / 32 barrier groups

// ---------- fp32 -> bf16(hi) + bf16(lo) Dekker split, RNE both ----------
__device__ __forceinline__ unsigned short bf16_rne(float f) {
    unsigned int u = __float_as_uint(f);
    unsigned int r = u + 0x7FFFu + ((u >> 16) & 1u);
    return (unsigned short)(r >> 16);
}
__device__ __forceinline__ void split1(float f, unsigned short& h, unsigned short& l) {
    unsigned short hb = bf16_rne(f);
    float fh = __uint_as_float(((unsigned int)hb) << 16);
    h = hb;
    l = bf16_rne(f - fh);
}

// tile layout: [rowtile16][kchunk32][lane64][j8]; lane = (k>>3 & 3)*16 + (row&15)
__device__ __forceinline__ size_t tpos(int r, int k) {
    int ct = r >> 4, colr = r & 15, kc = k >> 5, kg = (k >> 3) & 3, j = k & 7;
    return ((((size_t)ct * 32 + kc) * 64) + (kg * 16 + colr)) * 8 + j;
}

// ---------- device-scope grid barrier, two-level, monotonic epochs ----------
// Poll with RELAXED loads (no per-iteration buffer_inv — the round-6 storm);
// exactly one release fence (wbl2) before arrival and one acquire fence (inv)
// after exit, per block per barrier.
__device__ __forceinline__ void gbar(unsigned* cnt, unsigned* gen,
                                     unsigned* gcnt, unsigned ep) {
    __syncthreads();                       // block work done, vmcnt drained
    if (threadIdx.x == 0) {
        __builtin_amdgcn_fence(__ATOMIC_RELEASE, "agent");   // wbl2 once
        const int gid = blockIdx.x >> 5;   // 24 groups of 32 blocks
        unsigned a = __hip_atomic_fetch_add(&gcnt[gid * 16], 1u,
                        __ATOMIC_RELAXED, __HIP_MEMORY_SCOPE_AGENT);
        if (a == ep * 32u - 1u) {          // last in group
            unsigned r = __hip_atomic_fetch_add(cnt, 1u,
                            __ATOMIC_RELAXED, __HIP_MEMORY_SCOPE_AGENT);
            if (r == ep * (unsigned)NGRP - 1u)   // last group
                __hip_atomic_store(gen, ep, __ATOMIC_RELEASE,
                                   __HIP_MEMORY_SCOPE_AGENT);
        }
        while (__hip_atomic_load(gen, __ATOMIC_RELAXED,
                                 __HIP_MEMORY_SCOPE_AGENT) < ep)
            __builtin_amdgcn_s_sleep(8);
        __builtin_amdgcn_fence(__ATOMIC_ACQUIRE, "agent");   // inv once
    }
    __syncthreads();
}

struct KP {
    const float *emb, *w_ih, *w_hh, *b_ih, *b_hh, *w_proj, *b_proj, *h0;
    const int   *start;
    unsigned short *bpjh, *bpjl;
    unsigned short *gwh[4], *gwl[4];       // [l*2+m] m0=ih m1=hh
    unsigned short *hth, *htl;             // layer stride 65536 elems
    float *hbuf, *gpart, *logits, *red;
    int   *tok;
    unsigned *cnt, *gen, *gcnt;
    float *out_logp, *out_tok;
    int Vt, Tt;
};

__global__ void __launch_bounds__(NTHR, 4) k_persist(KP p) {
    const int bid = blockIdx.x, tid = threadIdx.x;
    const int wav = tid >> 6, lane = tid & 63;
    const int colr = lane & 15, kg = lane >> 4;
    unsigned ep = 0;
    __shared__ float sm[NTHR]; __shared__ int si[NTHR]; __shared__ float ss[NTHR];

    // ================= precompute (once per launch) =================
    for (int idx = bid * NTHR + tid; idx < NL * NB * HID; idx += NBLK * NTHR) {
        float v = p.h0[idx];
        p.hbuf[idx] = v;
        int l = idx >> 16, b = (idx >> 10) & 63, i = idx & 1023;
        unsigned short h, lo;
        split1(v, h, lo);
        size_t q = (size_t)l * 65536 + tpos(b, i);
        p.hth[q] = h; p.htl[q] = lo;
    }
    if (bid == 0 && tid < NB) p.tok[tid] = p.start[0];
    for (size_t idx = (size_t)bid * NTHR + tid; idx < (size_t)VPAD * 1024; idx += (size_t)NBLK * NTHR) {
        int r = (int)(idx >> 10), k = (int)(idx & 1023);
        float v = (r < p.Vt) ? p.w_proj[(size_t)r * 1024 + k] : 0.f;
        unsigned short h, l; split1(v, h, l);
        size_t q = tpos(r, k);
        p.bpjh[q] = h; p.bpjl[q] = l;
    }
    for (int w = 0; w < 4; ++w) {                 // w = l*2+m
        const float* W = (w & 1) ? p.w_hh + (size_t)(w >> 1) * TH3 * HID
                                 : p.w_ih + (size_t)(w >> 1) * TH3 * DIM;
        unsigned short* th = p.gwh[w];
        unsigned short* tl = p.gwl[w];
        for (size_t idx = (size_t)bid * NTHR + tid; idx < (size_t)TH3 * 1024; idx += (size_t)NBLK * NTHR) {
            int r = (int)(idx >> 10), k = (int)(idx & 1023);
            float v = W[(size_t)r * 1024 + k];
            unsigned short h, l; split1(v, h, l);
            size_t q = tpos(r, k);
            th[q] = h; tl[q] = l;
        }
    }
    gbar(p.cnt, p.gen, p.gcnt, ++ep);

    // ================= T-step loop =================
    for (int t = 0; t < p.Tt; ++t) {
        // ---- GRU layers ----
        for (int l = 0; l < NL; ++l) {
            {
                int u = bid * 4 + wav;                     // 0..3071
                int m = u / 1536, rem = u % 1536;
                int kcg = rem / 192, ct = rem % 192;
                int kc0 = kcg * 4;                         // K=128 per wave
                const bf16x8* B8h = (const bf16x8*)p.gwh[l * 2 + m];
                const bf16x8* B8l = (const bf16x8*)p.gwl[l * 2 + m];
                const unsigned short* Ath = (m == 0) ? p.hth : p.hth + (size_t)l * 65536;
                const unsigned short* Atl = (m == 0) ? p.htl : p.htl + (size_t)l * 65536;
                const bf16x8* A8h = (const bf16x8*)Ath;
                const bf16x8* A8l = (const bf16x8*)Atl;
                const bool gather = (l == 0 && m == 0);    // x = emb[tok]
                f32x4 acc[4];
#pragma unroll
                for (int mt = 0; mt < 4; ++mt) acc[mt] = (f32x4){0.f, 0.f, 0.f, 0.f};
#pragma unroll
                for (int i = 0; i < 4; ++i) {
                    int kc = kc0 + i;
                    bf16x8 bh = B8h[((size_t)ct * 32 + kc) * 64 + lane];
                    bf16x8 bl = B8l[((size_t)ct * 32 + kc) * 64 + lane];
#pragma unroll
                    for (int mt = 0; mt < 4; ++mt) {
                        bf16x8 ah, al;
                        if (gather) {
                            int brow = mt * 16 + colr;
                            int k = kc * 32 + kg * 8;
                            const float* er = p.emb + (size_t)p.tok[brow] * DIM + k;
                            float4 e0 = *(const float4*)er;
                            float4 e1 = *(const float4*)(er + 4);
                            float ev[8] = {e0.x, e0.y, e0.z, e0.w, e1.x, e1.y, e1.z, e1.w};
#pragma unroll
                            for (int j = 0; j < 8; ++j) {
                                unsigned short h, lo;
                                split1(ev[j], h, lo);
                                ah[j] = (short)h; al[j] = (short)lo;
                            }
                        } else {
                            ah = A8h[(mt * 32 + kc) * 64 + lane];
                            al = A8l[(mt * 32 + kc) * 64 + lane];
                        }
                        acc[mt] = __builtin_amdgcn_mfma_f32_16x16x32_bf16(ah, bh, acc[mt], 0, 0, 0);
                        acc[mt] = __builtin_amdgcn_mfma_f32_16x16x32_bf16(al, bh, acc[mt], 0, 0, 0);
                        acc[mt] = __builtin_amdgcn_mfma_f32_16x16x32_bf16(ah, bl, acc[mt], 0, 0, 0);
                    }
                }
                float* out = p.gpart + (size_t)(m * GKC + kcg) * 64 * TH3;
#pragma unroll
                for (int mt = 0; mt < 4; ++mt)
#pragma unroll
                    for (int r = 0; r < 4; ++r)
                        out[(size_t)(mt * 16 + kg * 4 + r) * TH3 + ct * 16 + colr] = acc[mt][r];
            }
            gbar(p.cnt, p.gen, p.gcnt, ++ep);
            // ---- gate ----
            {
                int idx = bid * NTHR + tid;
                if (idx < NB * HID) {
                    int b = idx >> 10, i = idx & 1023;
                    const float* bih = p.b_ih + (size_t)l * TH3;
                    const float* bhh = p.b_hh + (size_t)l * TH3;
                    float ir = bih[i], iz = bih[HID + i], in = bih[2 * HID + i];
                    float hr = bhh[i], hz = bhh[HID + i], hn = bhh[2 * HID + i];
#pragma unroll
                    for (int kc = 0; kc < GKC; ++kc) {
                        const float* gi = p.gpart + ((size_t)kc * 64 + b) * TH3;
                        const float* gh = p.gpart + ((size_t)(GKC + kc) * 64 + b) * TH3;
                        ir += gi[i]; iz += gi[HID + i]; in += gi[2 * HID + i];
                        hr += gh[i]; hz += gh[HID + i]; hn += gh[2 * HID + i];
                    }
                    float r = 1.f / (1.f + expf(-(ir + hr)));
                    float z = 1.f / (1.f + expf(-(iz + hz)));
                    float n = tanhf(in + r * hn);
                    float* hb = p.hbuf + (size_t)l * NB * HID;
                    float hold = hb[idx];
                    float hnew = (1.f - z) * n + z * hold;
                    hb[idx] = hnew;
                    unsigned short h, lo;
                    split1(hnew, h, lo);
                    size_t q = (size_t)l * 65536 + tpos(b, i);
                    p.hth[q] = h; p.htl[q] = lo;
                }
            }
            gbar(p.cnt, p.gen, p.gcnt, ++ep);
        }
        // ---- projection: col-tile units round-robin; wave handles mt=wav ----
        {
            const bf16x8* A8h = (const bf16x8*)(p.hth + 65536);
            const bf16x8* A8l = (const bf16x8*)(p.htl + 65536);
            const int mt = wav;
            for (int ct = bid; ct < NCT; ct += NBLK) {
                const bf16x8* B8h = (const bf16x8*)p.bpjh + (size_t)ct * 32 * 64 + lane;
                const bf16x8* B8l = (const bf16x8*)p.bpjl + (size_t)ct * 32 * 64 + lane;
                f32x4 acc = (f32x4){0.f, 0.f, 0.f, 0.f};
#pragma unroll 2
                for (int kc = 0; kc < 32; ++kc) {
                    bf16x8 bh = B8h[kc * 64];
                    bf16x8 bl = B8l[kc * 64];
                    bf16x8 ah = A8h[(mt * 32 + kc) * 64 + lane];
                    bf16x8 al = A8l[(mt * 32 + kc) * 64 + lane];
                    acc = __builtin_amdgcn_mfma_f32_16x16x32_bf16(ah, bh, acc, 0, 0, 0);
                    acc = __builtin_amdgcn_mfma_f32_16x16x32_bf16(al, bh, acc, 0, 0, 0);
                    acc = __builtin_amdgcn_mfma_f32_16x16x32_bf16(ah, bl, acc, 0, 0, 0);
                }
                int col = ct * 16 + colr;
                float bv = (col < p.Vt) ? p.b_proj[col] : 0.f;
#pragma unroll
                for (int r = 0; r < 4; ++r)
                    p.logits[(size_t)(mt * 16 + kg * 4 + r) * VPAD + col] = acc[r] + bv;
            }
        }
        gbar(p.cnt, p.gen, p.gcnt, ++ep);
        // ---- reduce: per-(b,chunk) max/argmax/sumexp ----
        {
            const int cs = (p.Vt + RCH - 1) / RCH;
            for (int u = bid; u < NB * RCH; u += NBLK) {
                int b = u >> 4, ch = u & 15;
                int v0 = ch * cs, v1 = min(v0 + cs, p.Vt);
                const float* row = p.logits + (size_t)b * VPAD;
                float m = -INFINITY; int mi = 0;
                for (int v = v0 + tid; v < v1; v += NTHR) {
                    float x = row[v];
                    if (x > m) { m = x; mi = v; }
                }
                sm[tid] = m; si[tid] = mi;
                __syncthreads();
                for (int s = 128; s > 0; s >>= 1) {
                    if (tid < s) {
                        float vo = sm[tid + s]; int io = si[tid + s];
                        if (vo > sm[tid] || (vo == sm[tid] && io < si[tid])) { sm[tid] = vo; si[tid] = io; }
                    }
                    __syncthreads();
                }
                float mb = sm[0];
                float a = 0.f;
                for (int v = v0 + tid; v < v1; v += NTHR) a += expf(row[v] - mb);
                ss[tid] = a;
                __syncthreads();
                for (int s = 128; s > 0; s >>= 1) {
                    if (tid < s) ss[tid] += ss[tid + s];
                    __syncthreads();
                }
                if (tid == 0)
                    ((float4*)p.red)[b * RCH + ch] = make_float4(mb, ss[0], (float)si[0], 0.f);
                __syncthreads();
            }
        }
        gbar(p.cnt, p.gen, p.gcnt, ++ep);
        // ---- final: logp write + token select ----
        {
            for (int u = bid; u < NB * 25; u += NBLK) {
                int b = u / 25, ch = u % 25;
                float mg = -INFINITY, ig = 0.f;
#pragma unroll
                for (int c = 0; c < RCH; ++c) {
                    float4 q = ((const float4*)p.red)[b * RCH + c];
                    if (q.x > mg) { mg = q.x; ig = q.z; }
                    else if (q.x == mg && q.z < ig) { ig = q.z; }
                }
                float sg = 0.f;
#pragma unroll
                for (int c = 0; c < RCH; ++c) {
                    float4 q = ((const float4*)p.red)[b * RCH + c];
                    sg += q.y * expf(q.x - mg);
                }
                float lse = mg + logf(sg);
                const float* row = p.logits + (size_t)b * VPAD;
                float* orow = p.out_logp + ((size_t)b * p.Tt + t) * p.Vt;
                int base = ch * 2048;
#pragma unroll
                for (int j = 0; j < 8; ++j) {
                    int v = base + tid + j * NTHR;
                    if (v < p.Vt) orow[v] = row[v] - lse;
                }
                if (ch == 0 && tid == 0) {
                    p.tok[b] = (int)ig;
                    p.out_tok[(size_t)b * p.Tt + t] = ig;
                }
            }
        }
        gbar(p.cnt, p.gen, p.gcnt, ++ep);
    }
}

// ================= fallback (round-1) path =================

__global__ __launch_bounds__(256) void k_init(const float* __restrict__ h0,
                                              const int* __restrict__ start_tok,
                                              float* hbuf, unsigned short* hhi,
                                              unsigned short* hlo, int* tok) {
    int idx = blockIdx.x * 256 + threadIdx.x;
    if (idx < NL * NB * HID) {
        float v = h0[idx];
        hbuf[idx] = v;
        split1(v, hhi[idx], hlo[idx]);
    }
    if (idx < NB) tok[idx] = start_tok[0];
}

__global__ __launch_bounds__(256) void k_prep_x(const float* __restrict__ emb,
                                                const int* __restrict__ tok,
                                                unsigned short* xhi, unsigned short* xlo) {
    int idx = blockIdx.x * 256 + threadIdx.x;
    int b = idx >> 10, k = idx & 1023;
    float v = emb[(size_t)tok[b] * DIM + k];
    split1(v, xhi[idx], xlo[idx]);
}

__device__ __forceinline__ void mm_wave(const unsigned short* __restrict__ Ahi,
                                        const unsigned short* __restrict__ Alo,
                                        const float* __restrict__ W,
                                        int Ntot, int col, int k0, int klen,
                                        f32x4* acc) {
    const int lane = threadIdx.x & 63;
    const int colr = lane & 15;
    const int kg   = lane >> 4;
    const int colc = col < Ntot ? col : Ntot - 1;
    const float* wrow = W + (size_t)colc * 1024;
    for (int k = k0; k < k0 + klen; k += 32) {
        int ka = k + kg * 8;
        float4 b0 = *(const float4*)(wrow + ka);
        float4 b1 = *(const float4*)(wrow + ka + 4);
        float bv[8] = {b0.x, b0.y, b0.z, b0.w, b1.x, b1.y, b1.z, b1.w};
        bf16x8 bhi, blo;
#pragma unroll
        for (int j = 0; j < 8; ++j) {
            unsigned short h, l;
            split1(bv[j], h, l);
            bhi[j] = (short)h;
            blo[j] = (short)l;
        }
#pragma unroll
        for (int mt = 0; mt < 4; ++mt) {
            const bf16x8 ahi = *(const bf16x8*)(Ahi + (((mt * 16 + colr) << 10) + ka));
            const bf16x8 alo = *(const bf16x8*)(Alo + (((mt * 16 + colr) << 10) + ka));
            acc[mt] = __builtin_amdgcn_mfma_f32_16x16x32_bf16(ahi, bhi, acc[mt], 0, 0, 0);
            acc[mt] = __builtin_amdgcn_mfma_f32_16x16x32_bf16(alo, bhi, acc[mt], 0, 0, 0);
            acc[mt] = __builtin_amdgcn_mfma_f32_16x16x32_bf16(ahi, blo, acc[mt], 0, 0, 0);
        }
    }
}

__global__ __launch_bounds__(256) void k_mm_gru(const unsigned short* __restrict__ Axhi,
                                                const unsigned short* __restrict__ Axlo,
                                                const unsigned short* __restrict__ Ahhi,
                                                const unsigned short* __restrict__ Ahlo,
                                                const float* __restrict__ Wih,
                                                const float* __restrict__ Whh,
                                                float* __restrict__ gpart) {
    const int mat = blockIdx.z;
    const int kc  = blockIdx.y;
    const int wav = threadIdx.x >> 6;
    const int lane = threadIdx.x & 63;
    const int col = blockIdx.x * 64 + wav * 16 + (lane & 15);
    const unsigned short* Ahi = mat ? Ahhi : Axhi;
    const unsigned short* Alo = mat ? Ahlo : Axlo;
    const float* W = mat ? Whh : Wih;
    f32x4 acc[4] = {{0.f,0.f,0.f,0.f},{0.f,0.f,0.f,0.f},{0.f,0.f,0.f,0.f},{0.f,0.f,0.f,0.f}};
    mm_wave(Ahi, Alo, W, TH3, col, kc * 512, 512, acc);
    float* out = gpart + (size_t)(mat * 2 + kc) * NB * TH3;
    const int kg = lane >> 4;
#pragma unroll
    for (int mt = 0; mt < 4; ++mt)
#pragma unroll
        for (int r = 0; r < 4; ++r)
            out[(size_t)(mt * 16 + kg * 4 + r) * TH3 + col] = acc[mt][r];
}

__global__ __launch_bounds__(256) void k_gate(const float* __restrict__ gpart,
                                              const float* __restrict__ bih,
                                              const float* __restrict__ bhh,
                                              float* hbuf, unsigned short* hhi,
                                              unsigned short* hlo) {
    int idx = blockIdx.x * 256 + threadIdx.x;
    int b = idx >> 10, i = idx & 1023;
    const float* g00 = gpart;
    const float* g01 = gpart + (size_t)1 * NB * TH3;
    const float* g10 = gpart + (size_t)2 * NB * TH3;
    const float* g11 = gpart + (size_t)3 * NB * TH3;
    size_t o = (size_t)b * TH3;
    float ir = g00[o + i]            + g01[o + i]            + bih[i];
    float iz = g00[o + HID + i]      + g01[o + HID + i]      + bih[HID + i];
    float in = g00[o + 2 * HID + i]  + g01[o + 2 * HID + i]  + bih[2 * HID + i];
    float hr = g10[o + i]            + g11[o + i]            + bhh[i];
    float hz = g10[o + HID + i]      + g11[o + HID + i]      + bhh[HID + i];
    float hn = g10[o + 2 * HID + i]  + g11[o + 2 * HID + i]  + bhh[2 * HID + i];
    float r = 1.f / (1.f + expf(-(ir + hr)));
    float z = 1.f / (1.f + expf(-(iz + hz)));
    float n = tanhf(in + r * hn);
    float hold = hbuf[idx];
    float hnew = (1.f - z) * n + z * hold;
    hbuf[idx] = hnew;
    split1(hnew, hhi[idx], hlo[idx]);
}

__global__ __launch_bounds__(256) void k_mm_proj(const unsigned short* __restrict__ Ahi,
                                                 const unsigned short* __restrict__ Alo,
                                                 const float* __restrict__ Wp,
                                                 const float* __restrict__ bp,
                                                 float* __restrict__ logits, int Vt) {
    const int wav = threadIdx.x >> 6;
    const int lane = threadIdx.x & 63;
    const int col = blockIdx.x * 64 + wav * 16 + (lane & 15);
    f32x4 acc[4] = {{0.f,0.f,0.f,0.f},{0.f,0.f,0.f,0.f},{0.f,0.f,0.f,0.f},{0.f,0.f,0.f,0.f}};
    mm_wave(Ahi, Alo, Wp, Vt, col, 0, 1024, acc);
    if (col < Vt) {
        float bv = bp[col];
        const int kg = lane >> 4;
#pragma unroll
        for (int mt = 0; mt < 4; ++mt)
#pragma unroll
            for (int r = 0; r < 4; ++r)
                logits[(size_t)(mt * 16 + kg * 4 + r) * Vt + col] = acc[mt][r] + bv;
    }
}

__global__ __launch_bounds__(256) void k_reduce(const float* __restrict__ logits,
                                                float* __restrict__ red, int Vt, int ldl) {
    const int b = blockIdx.y, ch = blockIdx.x, tid = threadIdx.x;
    const int cs = (Vt + RCH - 1) / RCH;
    const int v0 = ch * cs;
    const int v1 = min(v0 + cs, Vt);
    const float* row = logits + (size_t)b * ldl;
    float m = -INFINITY; int mi = 0;
    for (int v = v0 + tid; v < v1; v += 256) {
        float x = row[v];
        if (x > m) { m = x; mi = v; }
    }
    __shared__ float sm[256]; __shared__ int si[256]; __shared__ float ss[256];
    sm[tid] = m; si[tid] = mi;
    __syncthreads();
    for (int s = 128; s > 0; s >>= 1) {
        if (tid < s) {
            float vo = sm[tid + s]; int io = si[tid + s];
            if (vo > sm[tid] || (vo == sm[tid] && io < si[tid])) { sm[tid] = vo; si[tid] = io; }
        }
        __syncthreads();
    }
    float mb = sm[0];
    float acc = 0.f;
    for (int v = v0 + tid; v < v1; v += 256) acc += expf(row[v] - mb);
    ss[tid] = acc;
    __syncthreads();
    for (int s = 128; s > 0; s >>= 1) {
        if (tid < s) ss[tid] += ss[tid + s];
        __syncthreads();
    }
    if (tid == 0)
        ((float4*)red)[b * RCH + ch] = make_float4(mb, ss[0], (float)si[0], 0.f);
}

__global__ __launch_bounds__(256) void k_final(const float* __restrict__ logits,
                                               const float* __restrict__ red,
                                               float* __restrict__ out_logp,
                                               float* __restrict__ out_tok,
                                               int* __restrict__ toknext,
                                               int Vt, int ldl, int Tt, int t) {
    const int b = blockIdx.y, tid = threadIdx.x;
    float mg = -INFINITY, ig = 0.f;
#pragma unroll
    for (int c = 0; c < RCH; ++c) {
        float4 p = ((const float4*)red)[b * RCH + c];
        if (p.x > mg) { mg = p.x; ig = p.z; }
        else if (p.x == mg && p.z < ig) { ig = p.z; }
    }
    float sg = 0.f;
#pragma unroll
    for (int c = 0; c < RCH; ++c) {
        float4 p = ((const float4*)red)[b * RCH + c];
        sg += p.y * expf(p.x - mg);
    }
    float lse = mg + logf(sg);
    const float* row = logits + (size_t)b * ldl;
    float* orow = out_logp + ((size_t)b * Tt + t) * Vt;
    const int base = blockIdx.x * 2048;
#pragma unroll
    for (int j = 0; j < 8; ++j) {
        int v = base + tid + j * 256;
        if (v < Vt) orow[v] = row[v] - lse;
    }
    if (blockIdx.x == 0 && tid == 0) {
        toknext[b] = (int)ig;
        out_tok[(size_t)b * Tt + t] = ig;
    }
}

extern "C" void kernel_launch(void* const* d_in, const int* in_sizes, int n_in,
                              void* d_out, int out_size, void* d_ws, size_t ws_size,
                              hipStream_t stream) {
    const float* emb    = (const float*)d_in[0];
    const float* w_ih   = (const float*)d_in[1];
    const float* w_hh   = (const float*)d_in[2];
    const float* b_ih   = (const float*)d_in[3];
    const float* b_hh   = (const float*)d_in[4];
    const float* w_proj = (const float*)d_in[5];
    const float* b_proj = (const float*)d_in[6];
    const float* h0     = (const float*)d_in[7];
    const int*   start  = (const int*)d_in[9];

    const int Vt = in_sizes[5] / HID;                 // 50257
    const int Tt = (int)((size_t)out_size / ((size_t)NB * (Vt + 1)));  // 32

    float* out_logp = (float*)d_out;
    float* out_tok  = (float*)d_out + (size_t)NB * Tt * Vt;

    const size_t SZ_BPROJ = (size_t)NCT * 32 * 64 * 8 * 2;
    const size_t SZ_GRUW  = (size_t)(TH3 / 16) * 32 * 64 * 8 * 2;
    const size_t SZ_HT    = (size_t)65536 * 2;

    char* ws = (char*)d_ws;
    size_t used = 0;
    auto alloc = [&](size_t bytes) {
        char* p = ws + used;
        used += (bytes + 255) & ~(size_t)255;
        return p;
    };
    KP p;
    p.emb = emb; p.w_ih = w_ih; p.w_hh = w_hh; p.b_ih = b_ih; p.b_hh = b_hh;
    p.w_proj = w_proj; p.b_proj = b_proj; p.h0 = h0; p.start = start;
    p.out_logp = out_logp; p.out_tok = out_tok; p.Vt = Vt; p.Tt = Tt;

    p.logits = (float*)alloc((size_t)NB * VPAD * 4);
    p.bpjh = (unsigned short*)alloc(SZ_BPROJ);
    p.bpjl = (unsigned short*)alloc(SZ_BPROJ);
    for (int i = 0; i < 4; ++i) {
        p.gwh[i] = (unsigned short*)alloc(SZ_GRUW);
        p.gwl[i] = (unsigned short*)alloc(SZ_GRUW);
    }
    p.hth = (unsigned short*)alloc(NL * SZ_HT);
    p.htl = (unsigned short*)alloc(NL * SZ_HT);
    p.hbuf = (float*)alloc((size_t)NL * NB * HID * 4);
    p.gpart = (float*)alloc((size_t)2 * GKC * 64 * TH3 * 4);
    p.red = (float*)alloc((size_t)NB * RCH * 16);
    p.tok = (int*)alloc(256);
    unsigned* bar = (unsigned*)alloc(2048);
    p.cnt  = bar;              // [0]
    p.gen  = bar + 32;         // [32]
    p.gcnt = bar + 64;         // 24 groups, stride 16 unsigned (64B line each)

    if (ws_size >= used) {
        // ---- persistent single-kernel path ----
        hipMemsetAsync(bar, 0, 2048, stream);
        k_persist<<<NBLK, NTHR, 0, stream>>>(p);
    } else {
        // ---- fallback (round-1) path ----
        char* w = (char*)d_ws;
        float* logitsF       = (float*)w;  w += (size_t)NB * Vt * 4;
        unsigned short* a0hi = (unsigned short*)w;  w += (size_t)NB * DIM * 2;
        unsigned short* a0lo = (unsigned short*)w;  w += (size_t)NB * DIM * 2;
        float* hbufF         = (float*)w;  w += (size_t)NL * NB * HID * 4;
        unsigned short* hhi  = (unsigned short*)w;  w += (size_t)NL * NB * HID * 2;
        unsigned short* hlo  = (unsigned short*)w;  w += (size_t)NL * NB * HID * 2;
        float* gpartF        = (float*)w;  w += (size_t)4 * NB * TH3 * 4;
        float* redF          = (float*)w;  w += (size_t)NB * RCH * 16;
        int* tokF            = (int*)w;    w += 256;

        k_init<<<(NL * NB * HID + 255) / 256, 256, 0, stream>>>(h0, start, hbufF, hhi, hlo, tokF);
        for (int t = 0; t < Tt; ++t) {
            k_prep_x<<<NB * DIM / 256, 256, 0, stream>>>(emb, tokF, a0hi, a0lo);
            for (int l = 0; l < NL; ++l) {
                const unsigned short* Axhi = (l == 0) ? a0hi : hhi;
                const unsigned short* Axlo = (l == 0) ? a0lo : hlo;
                const unsigned short* Ahhi = hhi + (size_t)l * NB * HID;
                const unsigned short* Ahlo = hlo + (size_t)l * NB * HID;
                k_mm_gru<<<dim3(TH3 / 64, 2, 2), 256, 0, stream>>>(
                    Axhi, Axlo, Ahhi, Ahlo,
                    w_ih + (size_t)l * TH3 * DIM, w_hh + (size_t)l * TH3 * HID, gpartF);
                k_gate<<<NB * HID / 256, 256, 0, stream>>>(
                    gpartF, b_ih + (size_t)l * TH3, b_hh + (size_t)l * TH3,
                    hbufF + (size_t)l * NB * HID, hhi + (size_t)l * NB * HID,
                    hlo + (size_t)l * NB * HID);
            }
            k_mm_proj<<<dim3((Vt + 63) / 64, 1, 1), 256, 0, stream>>>(
                hhi + (size_t)NB * HID, hlo + (size_t)NB * HID, w_proj, b_proj, logitsF, Vt);
            k_reduce<<<dim3(RCH, NB), 256, 0, stream>>>(logitsF, redF, Vt, Vt);
            k_final<<<dim3((Vt + 2047) / 2048, NB), 256, 0, stream>>>(
                logitsF, redF, out_logp, out_tok, tokF, Vt, Vt, Tt, t);
        }
    }
}